// Round 2
// baseline (227.904 us; speedup 1.0000x reference)
//
#include <hip/hip_runtime.h>

constexpr int H = 4096;
constexpr int W = 4096;
constexpr int NPIX = H * W;          // 16,777,216
constexpr int NV   = NPIX / 4;       // float4 count: 4,194,304
constexpr int W4   = W / 4;          // 1024 float4 per row

// ---- block-wide sum reduction (wave64 shfl + LDS across waves) ----
__device__ __forceinline__ float blockReduceSum(float val) {
    __shared__ float smem[8];
    const int lane = threadIdx.x & 63;
    const int wid  = threadIdx.x >> 6;
    #pragma unroll
    for (int off = 32; off > 0; off >>= 1) val += __shfl_down(val, off, 64);
    __syncthreads();                 // protect smem reuse across calls
    if (lane == 0) smem[wid] = val;
    __syncthreads();
    val = (threadIdx.x < (blockDim.x >> 6)) ? smem[threadIdx.x] : 0.f;
    if (wid == 0) {
        #pragma unroll
        for (int off = 32; off > 0; off >>= 1) val += __shfl_down(val, off, 64);
    }
    return val;                      // valid in thread 0
}

// ---- 3x3 cross-correlation (zero-padded) for 4 contiguous pixels ----
__device__ __forceinline__ void conv_row4(const float* __restrict__ p, int h, int w4,
                                          const float f[9], float cv[4]) {
    float a0 = 0.f, a1 = 0.f, a2 = 0.f, a3 = 0.f;
    #pragma unroll
    for (int dh = -1; dh <= 1; ++dh) {
        const int r = h + dh;
        float4 c = make_float4(0.f, 0.f, 0.f, 0.f);
        float left = 0.f, right = 0.f;
        if ((unsigned)r < (unsigned)H) {
            const float* row = p + (size_t)r * W;
            c = reinterpret_cast<const float4*>(row)[w4];
            const int w0 = w4 * 4;
            left  = (w0 > 0)      ? row[w0 - 1] : 0.f;
            right = (w0 + 4 < W)  ? row[w0 + 4] : 0.f;
        }
        const float* fr = f + (dh + 1) * 3;
        a0 += fr[0] * left + fr[1] * c.x + fr[2] * c.y;
        a1 += fr[0] * c.x  + fr[1] * c.y + fr[2] * c.z;
        a2 += fr[0] * c.y  + fr[1] * c.z + fr[2] * c.w;
        a3 += fr[0] * c.z  + fr[1] * c.w + fr[2] * right;
    }
    cv[0] = a0; cv[1] = a1; cv[2] = a2; cv[3] = a3;
}

// ---- K1: rr0=sum r0^2, pAp=sum p*c, r0c=sum r0*c, cc=sum c*c ----
__global__ __launch_bounds__(256) void k1_sums(const float* __restrict__ r0,
                                               const float* __restrict__ p,
                                               const float* __restrict__ filt,
                                               float* __restrict__ sums) {
    float f[9];
    #pragma unroll
    for (int i = 0; i < 9; ++i) f[i] = filt[i];
    float rr0 = 0.f, pap = 0.f, r0c = 0.f, cc = 0.f;
    const int stride = gridDim.x * blockDim.x;
    for (int v = blockIdx.x * blockDim.x + threadIdx.x; v < NV; v += stride) {
        const int h  = v >> 10;
        const int w4 = v & (W4 - 1);
        const float4 rv = reinterpret_cast<const float4*>(r0)[v];
        const float4 pv = reinterpret_cast<const float4*>(p)[v];
        float cv[4];
        conv_row4(p, h, w4, f, cv);
        rr0 += rv.x * rv.x + rv.y * rv.y + rv.z * rv.z + rv.w * rv.w;
        pap += pv.x * cv[0] + pv.y * cv[1] + pv.z * cv[2] + pv.w * cv[3];
        r0c += rv.x * cv[0] + rv.y * cv[1] + rv.z * cv[2] + rv.w * cv[3];
        cc  += cv[0]*cv[0] + cv[1]*cv[1] + cv[2]*cv[2] + cv[3]*cv[3];
    }
    rr0 = blockReduceSum(rr0);
    pap = blockReduceSum(pap);
    r0c = blockReduceSum(r0c);
    cc  = blockReduceSum(cc);
    if (threadIdx.x == 0) {
        atomicAdd(&sums[0], rr0);
        atomicAdd(&sums[1], pap);
        atomicAdd(&sums[2], r0c);
        atomicAdd(&sums[3], cc);
    }
}

// ---- K2: r1 = r0 - alpha*c; p_new = r1 + beta*p; phi_new = phi + alpha*p ----
__global__ __launch_bounds__(256) void k2_update(const float* __restrict__ r0,
                                                 const float* __restrict__ p,
                                                 const float* __restrict__ phi,
                                                 const float* __restrict__ filt,
                                                 const float* __restrict__ sums,
                                                 float* __restrict__ out) {
    const float s0 = sums[0], s1 = sums[1], s2 = sums[2], s3 = sums[3];
    const float alpha = s0 / s1;
    const float r1s   = s0 - 2.f * alpha * s2 + alpha * alpha * s3;
    const float beta  = r1s / s0;
    float f[9];
    #pragma unroll
    for (int i = 0; i < 9; ++i) f[i] = filt[i];
    float4* __restrict__ r1_out  = reinterpret_cast<float4*>(out);
    float4* __restrict__ pn_out  = reinterpret_cast<float4*>(out + (size_t)NPIX);
    float4* __restrict__ phi_out = reinterpret_cast<float4*>(out + 2 * (size_t)NPIX);
    const int stride = gridDim.x * blockDim.x;
    for (int v = blockIdx.x * blockDim.x + threadIdx.x; v < NV; v += stride) {
        const int h  = v >> 10;
        const int w4 = v & (W4 - 1);
        float cv[4];
        conv_row4(p, h, w4, f, cv);
        const float4 rv = reinterpret_cast<const float4*>(r0)[v];
        const float4 pv = reinterpret_cast<const float4*>(p)[v];
        const float4 ph = reinterpret_cast<const float4*>(phi)[v];
        float4 r1;
        r1.x = fmaf(-alpha, cv[0], rv.x);
        r1.y = fmaf(-alpha, cv[1], rv.y);
        r1.z = fmaf(-alpha, cv[2], rv.z);
        r1.w = fmaf(-alpha, cv[3], rv.w);
        r1_out[v] = r1;
        float4 pn;
        pn.x = fmaf(beta, pv.x, r1.x);
        pn.y = fmaf(beta, pv.y, r1.y);
        pn.z = fmaf(beta, pv.z, r1.z);
        pn.w = fmaf(beta, pv.w, r1.w);
        pn_out[v] = pn;
        float4 pho;
        pho.x = fmaf(alpha, pv.x, ph.x);
        pho.y = fmaf(alpha, pv.y, ph.y);
        pho.z = fmaf(alpha, pv.z, ph.z);
        pho.w = fmaf(alpha, pv.w, ph.w);
        phi_out[v] = pho;
    }
    if (blockIdx.x == 0 && threadIdx.x == 0) out[3 * (size_t)NPIX] = r1s;
}

extern "C" void kernel_launch(void* const* d_in, const int* in_sizes, int n_in,
                              void* d_out, int out_size, void* d_ws, size_t ws_size,
                              hipStream_t stream) {
    const float* r0   = (const float*)d_in[0];
    const float* p    = (const float*)d_in[1];
    const float* phi  = (const float*)d_in[2];
    const float* filt = (const float*)d_in[3];
    float* out  = (float*)d_out;
    float* sums = (float*)d_ws;   // [0]=rr0 [1]=pAp [2]=r0c [3]=cc

    hipMemsetAsync(sums, 0, 4 * sizeof(float), stream);

    dim3 block(256);
    dim3 grid(2048);
    hipLaunchKernelGGL(k1_sums,   grid, block, 0, stream, r0, p, filt, sums);
    hipLaunchKernelGGL(k2_update, grid, block, 0, stream, r0, p, phi, filt, sums, out);
}

// Round 4
// 129.277 us; speedup vs baseline: 1.7629x; 1.7629x over previous
//
#include <hip/hip_runtime.h>

constexpr int H = 4096;
constexpr int W = 4096;
constexpr int NPIX = H * W;          // 16,777,216
constexpr int W4   = W / 4;          // 1024 float4 per row
constexpr int NBLK = 4 * H;          // 16384 blocks, quarter-row each

typedef float f32x4 __attribute__((ext_vector_type(4)));   // native vec for nt builtins

// ---- block-wide sum reduction (wave64 shfl + LDS across waves) ----
__device__ __forceinline__ float blockReduceSum(float val) {
    __shared__ float smem[16];
    const int lane = threadIdx.x & 63;
    const int wid  = threadIdx.x >> 6;
    const int nw   = blockDim.x >> 6;
    #pragma unroll
    for (int o = 32; o > 0; o >>= 1) val += __shfl_down(val, o, 64);
    __syncthreads();
    if (lane == 0) smem[wid] = val;
    __syncthreads();
    if (wid == 0) {
        val = (lane < nw) ? smem[lane] : 0.f;
        #pragma unroll
        for (int o = 8; o > 0; o >>= 1) val += __shfl_down(val, o, 64);
    }
    return val;                      // valid in thread 0
}

// 3-tap horizontal conv for a float4 given left/right edge scalars
__device__ __forceinline__ float4 rowconv(float l, float4 c, float r, float f0, float f1, float f2) {
    float4 o;
    o.x = f0 * l   + f1 * c.x + f2 * c.y;
    o.y = f0 * c.x + f1 * c.y + f2 * c.z;
    o.z = f0 * c.y + f1 * c.z + f2 * c.w;
    o.w = f0 * c.z + f1 * c.w + f2 * r;
    return o;
}

// ---- K1: per-block partial sums of rr0, pAp, r0c, cc  (c = conv(p)) ----
__global__ __launch_bounds__(256) void k1_sums(const float* __restrict__ r0,
                                               const float* __restrict__ p,
                                               const float* __restrict__ filt,
                                               float* __restrict__ partials) {
    const int b = blockIdx.x;
    const int h = b >> 2;
    const int w4 = ((b & 3) << 8) + threadIdx.x;   // 0..1023
    const int w0 = w4 << 2;

    const float* __restrict__ rowc = p + (size_t)h * W;
    const float* __restrict__ rowm = p + (size_t)(h > 0     ? h - 1 : 0    ) * W;
    const float* __restrict__ rowp = p + (size_t)(h < H - 1 ? h + 1 : H - 1) * W;
    const float* __restrict__ r0row = r0 + (size_t)h * W;
    const float mM = (h > 0)     ? 1.f : 0.f;
    const float pM = (h < H - 1) ? 1.f : 0.f;

    // all loads issued unconditionally (clamped addresses, masked after)
    const float4 cm = reinterpret_cast<const float4*>(rowm)[w4];
    const float4 cc4 = reinterpret_cast<const float4*>(rowc)[w4];
    const float4 cp = reinterpret_cast<const float4*>(rowp)[w4];
    const float4 rv = reinterpret_cast<const float4*>(r0row)[w4];
    const int li = (w0 > 0) ? w0 - 1 : 0;
    const int ri = (w0 + 4 < W) ? w0 + 4 : W - 1;
    float lm = rowm[li], lc = rowc[li], lp = rowp[li];
    float rm = rowm[ri], rc = rowc[ri], rp = rowp[ri];

    float f[9];
    #pragma unroll
    for (int i = 0; i < 9; ++i) f[i] = filt[i];

    const float lM = (w0 > 0) ? 1.f : 0.f;
    const float rM = (w0 + 4 < W) ? 1.f : 0.f;
    lm *= lM; lc *= lM; lp *= lM;
    rm *= rM; rc *= rM; rp *= rM;

    float4 cv = rowconv(lc, cc4, rc, f[3], f[4], f[5]);
    const float4 tm = rowconv(lm, cm, rm, f[0], f[1], f[2]);
    const float4 tp = rowconv(lp, cp, rp, f[6], f[7], f[8]);
    cv.x = fmaf(mM, tm.x, fmaf(pM, tp.x, cv.x));
    cv.y = fmaf(mM, tm.y, fmaf(pM, tp.y, cv.y));
    cv.z = fmaf(mM, tm.z, fmaf(pM, tp.z, cv.z));
    cv.w = fmaf(mM, tm.w, fmaf(pM, tp.w, cv.w));

    float rr0 = rv.x*rv.x + rv.y*rv.y + rv.z*rv.z + rv.w*rv.w;
    float pap = cc4.x*cv.x + cc4.y*cv.y + cc4.z*cv.z + cc4.w*cv.w;
    float r0c = rv.x*cv.x + rv.y*cv.y + rv.z*cv.z + rv.w*cv.w;
    float cc  = cv.x*cv.x + cv.y*cv.y + cv.z*cv.z + cv.w*cv.w;

    rr0 = blockReduceSum(rr0);
    pap = blockReduceSum(pap);
    r0c = blockReduceSum(r0c);
    cc  = blockReduceSum(cc);
    if (threadIdx.x == 0) {
        partials[0 * NBLK + b] = rr0;
        partials[1 * NBLK + b] = pap;
        partials[2 * NBLK + b] = r0c;
        partials[3 * NBLK + b] = cc;
    }
}

// ---- K_reduce: fold partials, compute alpha, beta, r1_sum ----
__global__ __launch_bounds__(1024) void k_reduce(const float* __restrict__ partials,
                                                 float* __restrict__ scalars) {
    float s[4];
    #pragma unroll
    for (int i = 0; i < 4; ++i) {
        float v = 0.f;
        for (int t = threadIdx.x; t < NBLK; t += 1024)
            v += partials[i * NBLK + t];
        s[i] = blockReduceSum(v);
    }
    if (threadIdx.x == 0) {
        const float rr0 = s[0], pap = s[1], r0c = s[2], cc = s[3];
        const float alpha = rr0 / pap;
        const float r1s   = rr0 - 2.f * alpha * r0c + alpha * alpha * cc;
        const float beta  = r1s / rr0;
        scalars[0] = alpha;
        scalars[1] = beta;
        scalars[2] = r1s;
    }
}

// ---- K2: r1 = r0 - alpha*c; p_new = r1 + beta*p; phi_new = phi + alpha*p ----
__global__ __launch_bounds__(256) void k2_update(const float* __restrict__ r0,
                                                 const float* __restrict__ p,
                                                 const float* __restrict__ phi,
                                                 const float* __restrict__ filt,
                                                 const float* __restrict__ scalars,
                                                 float* __restrict__ out) {
    const int b = blockIdx.x;
    const int h = b >> 2;
    const int w4 = ((b & 3) << 8) + threadIdx.x;
    const int w0 = w4 << 2;
    const size_t vv = (size_t)h * W4 + w4;

    const float alpha = scalars[0];
    const float beta  = scalars[1];

    const float* __restrict__ rowc = p + (size_t)h * W;
    const float* __restrict__ rowm = p + (size_t)(h > 0     ? h - 1 : 0    ) * W;
    const float* __restrict__ rowp = p + (size_t)(h < H - 1 ? h + 1 : H - 1) * W;
    const float mM = (h > 0)     ? 1.f : 0.f;
    const float pM = (h < H - 1) ? 1.f : 0.f;

    const float4 cm = reinterpret_cast<const float4*>(rowm)[w4];
    const float4 cc4 = reinterpret_cast<const float4*>(rowc)[w4];
    const float4 cp = reinterpret_cast<const float4*>(rowp)[w4];
    const float4 rv = reinterpret_cast<const float4*>(r0 + (size_t)h * W)[w4];
    const f32x4 phn = __builtin_nontemporal_load(
        reinterpret_cast<const f32x4*>(phi + (size_t)h * W) + w4);
    const int li = (w0 > 0) ? w0 - 1 : 0;
    const int ri = (w0 + 4 < W) ? w0 + 4 : W - 1;
    float lm = rowm[li], lc = rowc[li], lp = rowp[li];
    float rm = rowm[ri], rc = rowc[ri], rp = rowp[ri];

    float f[9];
    #pragma unroll
    for (int i = 0; i < 9; ++i) f[i] = filt[i];

    const float lM = (w0 > 0) ? 1.f : 0.f;
    const float rM = (w0 + 4 < W) ? 1.f : 0.f;
    lm *= lM; lc *= lM; lp *= lM;
    rm *= rM; rc *= rM; rp *= rM;

    float4 cv = rowconv(lc, cc4, rc, f[3], f[4], f[5]);
    const float4 tm = rowconv(lm, cm, rm, f[0], f[1], f[2]);
    const float4 tp = rowconv(lp, cp, rp, f[6], f[7], f[8]);
    cv.x = fmaf(mM, tm.x, fmaf(pM, tp.x, cv.x));
    cv.y = fmaf(mM, tm.y, fmaf(pM, tp.y, cv.y));
    cv.z = fmaf(mM, tm.z, fmaf(pM, tp.z, cv.z));
    cv.w = fmaf(mM, tm.w, fmaf(pM, tp.w, cv.w));

    f32x4 r1;
    r1.x = fmaf(-alpha, cv.x, rv.x);
    r1.y = fmaf(-alpha, cv.y, rv.y);
    r1.z = fmaf(-alpha, cv.z, rv.z);
    r1.w = fmaf(-alpha, cv.w, rv.w);
    f32x4 pn;
    pn.x = fmaf(beta, cc4.x, r1.x);
    pn.y = fmaf(beta, cc4.y, r1.y);
    pn.z = fmaf(beta, cc4.z, r1.z);
    pn.w = fmaf(beta, cc4.w, r1.w);
    f32x4 pho;
    pho.x = fmaf(alpha, cc4.x, phn.x);
    pho.y = fmaf(alpha, cc4.y, phn.y);
    pho.z = fmaf(alpha, cc4.z, phn.z);
    pho.w = fmaf(alpha, cc4.w, phn.w);

    f32x4* __restrict__ r1_out  = reinterpret_cast<f32x4*>(out);
    f32x4* __restrict__ pn_out  = reinterpret_cast<f32x4*>(out + (size_t)NPIX);
    f32x4* __restrict__ phi_out = reinterpret_cast<f32x4*>(out + 2 * (size_t)NPIX);
    __builtin_nontemporal_store(r1,  r1_out  + vv);
    __builtin_nontemporal_store(pn,  pn_out  + vv);
    __builtin_nontemporal_store(pho, phi_out + vv);

    if (b == 0 && threadIdx.x == 0) out[3 * (size_t)NPIX] = scalars[2];
}

extern "C" void kernel_launch(void* const* d_in, const int* in_sizes, int n_in,
                              void* d_out, int out_size, void* d_ws, size_t ws_size,
                              hipStream_t stream) {
    const float* r0   = (const float*)d_in[0];
    const float* p    = (const float*)d_in[1];
    const float* phi  = (const float*)d_in[2];
    const float* filt = (const float*)d_in[3];
    float* out      = (float*)d_out;
    float* partials = (float*)d_ws;                 // 4 * NBLK floats
    float* scalars  = partials + 4 * NBLK;          // alpha, beta, r1_sum

    hipLaunchKernelGGL(k1_sums,  dim3(NBLK), dim3(256),  0, stream, r0, p, filt, partials);
    hipLaunchKernelGGL(k_reduce, dim3(1),    dim3(1024), 0, stream, partials, scalars);
    hipLaunchKernelGGL(k2_update,dim3(NBLK), dim3(256),  0, stream, r0, p, phi, filt, scalars, out);
}

// Round 6
// 124.637 us; speedup vs baseline: 1.8285x; 1.0372x over previous
//
#include <hip/hip_runtime.h>

constexpr int H = 4096;
constexpr int W = 4096;
constexpr int NPIX = H * W;           // 16,777,216
constexpr int W4   = W / 4;           // 1024 float4 per row
constexpr int NUNIT = 4 * H;          // 16384 quarter-row units
constexpr int K1_BLOCKS = 2048;
constexpr int K1_UNITS  = NUNIT / K1_BLOCKS;   // 8 units (2 rows) per block

typedef float f32x4 __attribute__((ext_vector_type(4)));

// ---- wave64 reduce of 4 values ----
__device__ __forceinline__ void waveRed4(float& a, float& b, float& c, float& d) {
    #pragma unroll
    for (int o = 32; o > 0; o >>= 1) {
        a += __shfl_down(a, o, 64);
        b += __shfl_down(b, o, 64);
        c += __shfl_down(c, o, 64);
        d += __shfl_down(d, o, 64);
    }
}

// 3-tap horizontal conv for a float4 given left/right edge scalars
__device__ __forceinline__ float4 rowconv(float l, float4 c, float r, float f0, float f1, float f2) {
    float4 o;
    o.x = f0 * l   + f1 * c.x + f2 * c.y;
    o.y = f0 * c.x + f1 * c.y + f2 * c.z;
    o.z = f0 * c.y + f1 * c.z + f2 * c.w;
    o.w = f0 * c.z + f1 * c.w + f2 * r;
    return o;
}

// compute conv(p) float4 + center p float4 for unit u (quarter-row)
__device__ __forceinline__ void conv_unit(const float* __restrict__ p,
                                          const float f[9], int u,
                                          float4& cv_out, float4& pc_out) {
    const int h  = u >> 2;
    const int w4 = ((u & 3) << 8) + threadIdx.x;
    const int w0 = w4 << 2;

    const float* __restrict__ rowc = p + (size_t)h * W;
    const float* __restrict__ rowm = p + (size_t)(h > 0     ? h - 1 : 0    ) * W;
    const float* __restrict__ rowp = p + (size_t)(h < H - 1 ? h + 1 : H - 1) * W;
    const float mM = (h > 0)     ? 1.f : 0.f;
    const float pM = (h < H - 1) ? 1.f : 0.f;

    const float4 cm  = reinterpret_cast<const float4*>(rowm)[w4];
    const float4 cc4 = reinterpret_cast<const float4*>(rowc)[w4];
    const float4 cp  = reinterpret_cast<const float4*>(rowp)[w4];
    const int li = (w0 > 0) ? w0 - 1 : 0;
    const int ri = (w0 + 4 < W) ? w0 + 4 : W - 1;
    float lm = rowm[li], lc = rowc[li], lp = rowp[li];
    float rm = rowm[ri], rc = rowc[ri], rp = rowp[ri];

    const float lM = (w0 > 0) ? 1.f : 0.f;
    const float rM = (w0 + 4 < W) ? 1.f : 0.f;
    lm *= lM; lc *= lM; lp *= lM;
    rm *= rM; rc *= rM; rp *= rM;

    float4 cv = rowconv(lc, cc4, rc, f[3], f[4], f[5]);
    const float4 tm = rowconv(lm, cm, rm, f[0], f[1], f[2]);
    const float4 tp = rowconv(lp, cp, rp, f[6], f[7], f[8]);
    cv.x = fmaf(mM, tm.x, fmaf(pM, tp.x, cv.x));
    cv.y = fmaf(mM, tm.y, fmaf(pM, tp.y, cv.y));
    cv.z = fmaf(mM, tm.z, fmaf(pM, tp.z, cv.z));
    cv.w = fmaf(mM, tm.w, fmaf(pM, tp.w, cv.w));

    cv_out = cv;
    pc_out = cc4;
}

// ---- K1: per-block partial sums over 8 units (2 adjacent rows) ----
__global__ __launch_bounds__(256) void k1_sums(const float* __restrict__ r0,
                                               const float* __restrict__ p,
                                               const float* __restrict__ filt,
                                               float* __restrict__ partials) {
    __shared__ float sred[4][4];
    float f[9];
    #pragma unroll
    for (int i = 0; i < 9; ++i) f[i] = filt[i];

    const int lane = threadIdx.x & 63;
    const int wid  = threadIdx.x >> 6;

    float s0 = 0.f, s1 = 0.f, s2 = 0.f, s3 = 0.f;
    const int u0 = blockIdx.x * K1_UNITS;
    #pragma unroll 4
    for (int i = 0; i < K1_UNITS; ++i) {
        const int u = u0 + i;
        const int h  = u >> 2;
        const int w4 = ((u & 3) << 8) + threadIdx.x;
        float4 cv, pc;
        conv_unit(p, f, u, cv, pc);
        const float4 rv = reinterpret_cast<const float4*>(r0 + (size_t)h * W)[w4];
        s0 += rv.x*rv.x + rv.y*rv.y + rv.z*rv.z + rv.w*rv.w;
        s1 += pc.x*cv.x + pc.y*cv.y + pc.z*cv.z + pc.w*cv.w;
        s2 += rv.x*cv.x + rv.y*cv.y + rv.z*cv.z + rv.w*cv.w;
        s3 += cv.x*cv.x + cv.y*cv.y + cv.z*cv.z + cv.w*cv.w;
    }
    waveRed4(s0, s1, s2, s3);
    if (lane == 0) { sred[wid][0] = s0; sred[wid][1] = s1; sred[wid][2] = s2; sred[wid][3] = s3; }
    __syncthreads();
    if (threadIdx.x == 0) {
        f32x4 pv;
        pv.x = sred[0][0] + sred[1][0] + sred[2][0] + sred[3][0];
        pv.y = sred[0][1] + sred[1][1] + sred[2][1] + sred[3][1];
        pv.z = sred[0][2] + sred[1][2] + sred[2][2] + sred[3][2];
        pv.w = sred[0][3] + sred[1][3] + sred[2][3] + sred[3][3];
        reinterpret_cast<f32x4*>(partials)[blockIdx.x] = pv;
    }
}

// ---- K_reduce: fold 2048 partial-vectors, compute alpha, beta, r1_sum ----
__global__ __launch_bounds__(1024) void k_reduce(const float* __restrict__ partials,
                                                 float* __restrict__ scalars) {
    __shared__ float sred[16][4];
    const int lane = threadIdx.x & 63;
    const int wid  = threadIdx.x >> 6;

    f32x4 acc = reinterpret_cast<const f32x4*>(partials)[threadIdx.x]
              + reinterpret_cast<const f32x4*>(partials)[threadIdx.x + 1024];
    float s0 = acc.x, s1 = acc.y, s2 = acc.z, s3 = acc.w;
    waveRed4(s0, s1, s2, s3);
    if (lane == 0) { sred[wid][0] = s0; sred[wid][1] = s1; sred[wid][2] = s2; sred[wid][3] = s3; }
    __syncthreads();
    if (threadIdx.x == 0) {
        float rr0 = 0.f, pap = 0.f, r0c = 0.f, cc = 0.f;
        #pragma unroll
        for (int wv = 0; wv < 16; ++wv) {
            rr0 += sred[wv][0]; pap += sred[wv][1];
            r0c += sred[wv][2]; cc  += sred[wv][3];
        }
        const float alpha = rr0 / pap;
        const float r1s   = rr0 - 2.f * alpha * r0c + alpha * alpha * cc;
        scalars[0] = alpha;
        scalars[1] = r1s / rr0;   // beta
        scalars[2] = r1s;
    }
}

// ---- K2: r1 = r0 - alpha*c; p_new = r1 + beta*p; phi_new = phi + alpha*p ----
__global__ __launch_bounds__(256) void k2_update(const float* __restrict__ r0,
                                                 const float* __restrict__ p,
                                                 const float* __restrict__ phi,
                                                 const float* __restrict__ filt,
                                                 const float* __restrict__ scalars,
                                                 float* __restrict__ out) {
    const int b = blockIdx.x;
    const int h = b >> 2;
    const int w4 = ((b & 3) << 8) + threadIdx.x;
    const size_t vv = (size_t)h * W4 + w4;

    const float alpha = scalars[0];
    const float beta  = scalars[1];

    float f[9];
    #pragma unroll
    for (int i = 0; i < 9; ++i) f[i] = filt[i];

    float4 cv, pc;
    conv_unit(p, f, b, cv, pc);
    const float4 rv = reinterpret_cast<const float4*>(r0 + (size_t)h * W)[w4];
    const f32x4 ph = __builtin_nontemporal_load(
        reinterpret_cast<const f32x4*>(phi) + vv);

    f32x4 r1;
    r1.x = fmaf(-alpha, cv.x, rv.x);
    r1.y = fmaf(-alpha, cv.y, rv.y);
    r1.z = fmaf(-alpha, cv.z, rv.z);
    r1.w = fmaf(-alpha, cv.w, rv.w);
    f32x4 pn;
    pn.x = fmaf(beta, pc.x, r1.x);
    pn.y = fmaf(beta, pc.y, r1.y);
    pn.z = fmaf(beta, pc.z, r1.z);
    pn.w = fmaf(beta, pc.w, r1.w);
    f32x4 pho;
    pho.x = fmaf(alpha, pc.x, ph.x);
    pho.y = fmaf(alpha, pc.y, ph.y);
    pho.z = fmaf(alpha, pc.z, ph.z);
    pho.w = fmaf(alpha, pc.w, ph.w);

    f32x4* __restrict__ r1_out  = reinterpret_cast<f32x4*>(out);
    f32x4* __restrict__ pn_out  = reinterpret_cast<f32x4*>(out + (size_t)NPIX);
    f32x4* __restrict__ phi_out = reinterpret_cast<f32x4*>(out + 2 * (size_t)NPIX);
    __builtin_nontemporal_store(r1,  r1_out  + vv);
    __builtin_nontemporal_store(pn,  pn_out  + vv);
    __builtin_nontemporal_store(pho, phi_out + vv);

    if (b == 0 && threadIdx.x == 0) out[3 * (size_t)NPIX] = scalars[2];
}

extern "C" void kernel_launch(void* const* d_in, const int* in_sizes, int n_in,
                              void* d_out, int out_size, void* d_ws, size_t ws_size,
                              hipStream_t stream) {
    const float* r0   = (const float*)d_in[0];
    const float* p    = (const float*)d_in[1];
    const float* phi  = (const float*)d_in[2];
    const float* filt = (const float*)d_in[3];
    float* out      = (float*)d_out;
    float* partials = (float*)d_ws;                 // 4 * K1_BLOCKS floats
    float* scalars  = partials + 4 * K1_BLOCKS;     // alpha, beta, r1_sum

    hipLaunchKernelGGL(k1_sums,  dim3(K1_BLOCKS), dim3(256),  0, stream, r0, p, filt, partials);
    hipLaunchKernelGGL(k_reduce, dim3(1),         dim3(1024), 0, stream, partials, scalars);
    hipLaunchKernelGGL(k2_update,dim3(NUNIT),     dim3(256),  0, stream, r0, p, phi, filt, scalars, out);
}